// Round 1
// baseline (6285.853 us; speedup 1.0000x reference)
//
#include <hip/hip_runtime.h>

// Transformer LM forward, MI355X gfx950.
// Sizes (fixed): V=32000 D=1024 H=16 L=8 FF=4096 T=1024 B=2, HD=64, M=B*T=2048.
#define VV 32000
#define DD 1024
#define HH 16
#define LL 8
#define FFD 4096
#define TT 1024
#define BBATCH 2
#define MM (BBATCH * TT)  // 2048

typedef __attribute__((ext_vector_type(4))) float f32x4;
typedef __attribute__((ext_vector_type(8))) short bf16x8;

__device__ __forceinline__ float bf2f(unsigned short u) {
    union { unsigned int i; float f; } c;
    c.i = ((unsigned int)u) << 16;
    return c.f;
}
__device__ __forceinline__ unsigned short f2bf(float f) {
    union { float f; unsigned int i; } c;
    c.f = f;
    unsigned int i = c.i;
    return (unsigned short)((i + 0x7fffu + ((i >> 16) & 1u)) >> 16);  // RNE
}

// ---------------------------------------------------------------- embedding
__global__ __launch_bounds__(256) void k_embed(const int* __restrict__ idx,
                                               const float* __restrict__ tok,
                                               const float* __restrict__ pos,
                                               float* __restrict__ x) {
    int bt = blockIdx.x;           // 0..2047 = b*T + t
    int tid = threadIdx.x;         // 256 threads * float4 = 1024 floats
    int tok_id = idx[bt];
    int tpos = bt & (TT - 1);
    float4 a = ((const float4*)(tok + (size_t)tok_id * DD))[tid];
    float4 p = ((const float4*)(pos + (size_t)tpos * DD))[tid];
    float4 r;
    r.x = a.x + p.x; r.y = a.y + p.y; r.z = a.z + p.z; r.w = a.w + p.w;
    ((float4*)(x + (size_t)bt * DD))[tid] = r;
}

// ---------------------------------------------------------------- layernorm (f32 in, bf16 out)
__global__ __launch_bounds__(256) void k_ln(const float* __restrict__ x,
                                            const float* __restrict__ w,
                                            const float* __restrict__ b,
                                            unsigned short* __restrict__ out) {
    __shared__ float red[4];
    int row = blockIdx.x, t = threadIdx.x;
    const float* xr = x + (size_t)row * DD;
    float4 v = ((const float4*)xr)[t];
    float s = v.x + v.y + v.z + v.w;
#pragma unroll
    for (int off = 32; off; off >>= 1) s += __shfl_xor(s, off);
    if ((t & 63) == 0) red[t >> 6] = s;
    __syncthreads();
    float mean = (red[0] + red[1] + red[2] + red[3]) * (1.0f / DD);
    __syncthreads();
    float d0 = v.x - mean, d1 = v.y - mean, d2 = v.z - mean, d3 = v.w - mean;
    float s2 = d0 * d0 + d1 * d1 + d2 * d2 + d3 * d3;
#pragma unroll
    for (int off = 32; off; off >>= 1) s2 += __shfl_xor(s2, off);
    if ((t & 63) == 0) red[t >> 6] = s2;
    __syncthreads();
    float var = (red[0] + red[1] + red[2] + red[3]) * (1.0f / DD);
    float r = rsqrtf(var + 1e-5f);
    float4 wv = ((const float4*)w)[t];
    float4 bv = ((const float4*)b)[t];
    union { unsigned short u[4]; uint2 v2; } pk;
    pk.u[0] = f2bf(d0 * r * wv.x + bv.x);
    pk.u[1] = f2bf(d1 * r * wv.y + bv.y);
    pk.u[2] = f2bf(d2 * r * wv.z + bv.z);
    pk.u[3] = f2bf(d3 * r * wv.w + bv.w);
    *((uint2*)(out + (size_t)row * DD + t * 4)) = pk.v2;
}

// ---------------------------------------------------------------- GEMM core
// C[M,N] = A[M,K](bf16) @ W[K,N](f32, converted to bf16 in staging) + bias
// EPI: 0 = bf16 out, 1 = bf16 out + ReLU, 2 = f32 residual accumulate (outf += ...)
// Tile 128x128, BK=32, 256 threads = 4 waves in 2x2, each wave 64x64 via 4x4
// mfma_f32_16x16x32_bf16 fragments. k-mapping phi(g,j)=8g+j used identically
// for A and B fragments (permutation-invariant => correct for any true HW k order).
template <int EPI>
__device__ __forceinline__ void gemm_core(const unsigned short* __restrict__ A,
                                          const float* __restrict__ W,
                                          const float* __restrict__ bias,
                                          unsigned short* __restrict__ outb,
                                          float* __restrict__ outf, int K, int N) {
    // A tile: [128 rows][pitch 40 bf16] (pitch 80B: 16B-aligned rows, 2-way-max banks)
    __shared__ __align__(16) unsigned short Alds[128][40];
    // B tile: [g=k/8][n][k%8] so a fragment read is one contiguous 16B chunk
    __shared__ __align__(16) unsigned short Blds[4][128][8];

    int t = threadIdx.x;
    int bn = blockIdx.x * 128, bm = blockIdx.y * 128;
    int lane = t & 63, w = t >> 6, wm = w >> 1, wn = w & 1;
    int lr = lane & 15, lg = lane >> 4;

    f32x4 acc[4][4];
#pragma unroll
    for (int mi = 0; mi < 4; ++mi)
#pragma unroll
        for (int ni = 0; ni < 4; ++ni) acc[mi][ni] = (f32x4){0.f, 0.f, 0.f, 0.f};

    int ar = t >> 1, ao = (t & 1) << 4;  // each thread: 16 bf16 of one A row
    const unsigned short* Ap = A + (size_t)(bm + ar) * K + ao;
    int nn = t & 127, g0 = t >> 7;       // B staging: column nn, k-octets g0, g0+2

    for (int kt = 0; kt < K; kt += 32) {
        // --- stage A (bf16 global -> LDS)
        uint4 a0 = *(const uint4*)(Ap + kt);
        uint4 a1 = *(const uint4*)(Ap + kt + 8);
        *(uint4*)&Alds[ar][ao] = a0;
        *(uint4*)&Alds[ar][ao + 8] = a1;
        // --- stage B (f32 global, coalesced column loads -> cvt -> b128 write)
#pragma unroll
        for (int gg = 0; gg < 2; ++gg) {
            int g = g0 + gg * 2;
            const float* Wp = W + (size_t)(kt + g * 8) * N + bn + nn;
            float f[8];
#pragma unroll
            for (int i = 0; i < 8; ++i) f[i] = Wp[(size_t)i * N];
            union { unsigned short u[8]; uint4 v; } pk;
#pragma unroll
            for (int i = 0; i < 8; ++i) pk.u[i] = f2bf(f[i]);
            *(uint4*)&Blds[g][nn][0] = pk.v;
        }
        __syncthreads();

        bf16x8 af[4], bfr[4];
#pragma unroll
        for (int mi = 0; mi < 4; ++mi)
            af[mi] = *(const bf16x8*)&Alds[wm * 64 + mi * 16 + lr][lg * 8];
#pragma unroll
        for (int ni = 0; ni < 4; ++ni)
            bfr[ni] = *(const bf16x8*)&Blds[lg][wn * 64 + ni * 16 + lr][0];
#pragma unroll
        for (int mi = 0; mi < 4; ++mi)
#pragma unroll
            for (int ni = 0; ni < 4; ++ni)
                acc[mi][ni] = __builtin_amdgcn_mfma_f32_16x16x32_bf16(
                    af[mi], bfr[ni], acc[mi][ni], 0, 0, 0);
        __syncthreads();
    }

    // --- epilogue. C/D layout: col = lane&15, row = (lane>>4)*4 + j (verified)
#pragma unroll
    for (int mi = 0; mi < 4; ++mi) {
#pragma unroll
        for (int ni = 0; ni < 4; ++ni) {
            int col = bn + wn * 64 + ni * 16 + lr;
            float bv = bias[col];
            int row0 = bm + wm * 64 + mi * 16 + lg * 4;
#pragma unroll
            for (int j = 0; j < 4; ++j) {
                float val = acc[mi][ni][j] + bv;
                if (EPI == 1) val = fmaxf(val, 0.0f);
                if (EPI == 2) {
                    float* p = outf + (size_t)(row0 + j) * N + col;
                    *p = *p + val;
                } else {
                    outb[(size_t)(row0 + j) * N + col] = f2bf(val);
                }
            }
        }
    }
}

template <int EPI>
__global__ __launch_bounds__(256) void k_gemm(const unsigned short* __restrict__ A,
                                              const float* __restrict__ W,
                                              const float* __restrict__ bias,
                                              unsigned short* __restrict__ outb,
                                              float* __restrict__ outf, int K, int N) {
    gemm_core<EPI>(A, W, bias, outb, outf, K, N);
}

// fused Q/K/V: gridDim.z selects the weight/bias/output triple (same A => L2 reuse)
__global__ __launch_bounds__(256) void k_gemm_qkv(
    const unsigned short* __restrict__ A, const float* __restrict__ W0,
    const float* __restrict__ W1, const float* __restrict__ W2,
    const float* __restrict__ b0, const float* __restrict__ b1,
    const float* __restrict__ b2, unsigned short* __restrict__ o0,
    unsigned short* __restrict__ o1, unsigned short* __restrict__ o2, int K, int N) {
    const float* W = (blockIdx.z == 0) ? W0 : ((blockIdx.z == 1) ? W1 : W2);
    const float* bs = (blockIdx.z == 0) ? b0 : ((blockIdx.z == 1) ? b1 : b2);
    unsigned short* ob = (blockIdx.z == 0) ? o0 : ((blockIdx.z == 1) ? o1 : o2);
    gemm_core<0>(A, W, bs, ob, nullptr, K, N);
}

// ---------------------------------------------------------------- attention
// One wave per (b, h, q-row). Scores in LDS (f32), online over 64-key chunks,
// full-precision softmax, then PV with lane = head-dim.
__global__ __launch_bounds__(256) void k_attn(const unsigned short* __restrict__ Q,
                                              const unsigned short* __restrict__ Kb,
                                              const unsigned short* __restrict__ Vb,
                                              unsigned short* __restrict__ O) {
    __shared__ float q_s[4][64];
    __shared__ float p_s[4][TT];
    int t = threadIdx.x, lane = t & 63, w = t >> 6;
    int gw = blockIdx.x * 4 + w;   // 0..32767
    int tq = gw & (TT - 1);
    int bh = gw >> 10;             // 0..31
    int b = bh >> 4, h = bh & 15;
    size_t base = ((size_t)b * TT) * DD + (size_t)h * 64;

    q_s[w][lane] = bf2f(Q[base + (size_t)tq * DD + lane]);
    __syncthreads();  // uniform, before any divergent loops

    float qreg[64];
#pragma unroll
    for (int d = 0; d < 64; ++d) qreg[d] = q_s[w][d];

    int nj = tq + 1;
    int njr = (nj + 63) & ~63;
    float m = -1e30f;
    for (int jb = 0; jb < njr; jb += 64) {
        int j = jb + lane;
        float s = -1e30f;
        if (j < nj) {
            const unsigned short* kp = Kb + base + (size_t)j * DD;
            float acc = 0.f;
#pragma unroll
            for (int d = 0; d < 64; d += 8) {
                uint4 raw = *(const uint4*)(kp + d);
                const unsigned short* ku = (const unsigned short*)&raw;
#pragma unroll
                for (int i = 0; i < 8; ++i) acc += qreg[d + i] * bf2f(ku[i]);
            }
            s = acc * 0.125f;  // 1/sqrt(64)
        }
        p_s[w][j] = s;
        m = fmaxf(m, s);
    }
#pragma unroll
    for (int off = 32; off; off >>= 1) m = fmaxf(m, __shfl_xor(m, off));

    float sum = 0.f;
    for (int jb = 0; jb < njr; jb += 64) {
        int j = jb + lane;
        float p = p_s[w][j];
        p = (j < nj) ? __expf(p - m) : 0.f;
        p_s[w][j] = p;
        sum += p;
    }
#pragma unroll
    for (int off = 32; off; off >>= 1) sum += __shfl_xor(sum, off);
    float inv = 1.0f / sum;

    const unsigned short* vp = Vb + base + lane;  // lane = head dim
    float a0 = 0.f, a1 = 0.f, a2 = 0.f, a3 = 0.f;
    int j = 0;
    for (; j + 4 <= nj; j += 4) {
        a0 += p_s[w][j + 0] * bf2f(vp[(size_t)(j + 0) * DD]);
        a1 += p_s[w][j + 1] * bf2f(vp[(size_t)(j + 1) * DD]);
        a2 += p_s[w][j + 2] * bf2f(vp[(size_t)(j + 2) * DD]);
        a3 += p_s[w][j + 3] * bf2f(vp[(size_t)(j + 3) * DD]);
    }
    for (; j < nj; ++j) a0 += p_s[w][j] * bf2f(vp[(size_t)j * DD]);
    O[base + (size_t)tq * DD + lane] = f2bf(((a0 + a1) + (a2 + a3)) * inv);
}

// ---------------------------------------------------------------- head
__global__ __launch_bounds__(256) void k_head_init(const float* __restrict__ hb,
                                                   float* __restrict__ out) {
    int v = blockIdx.x * 256 + threadIdx.x;  // grid 125 -> exactly 32000
    float x = hb[v];
    out[v] = x;
    out[VV + v] = x;
}

__global__ __launch_bounds__(256) void k_head(const unsigned short* __restrict__ xl,
                                              const float* __restrict__ Wh,
                                              float* __restrict__ out) {
    __shared__ float xs[2][128];
    int t = threadIdx.x;
    int dbase = blockIdx.y * 128;
    if (t < 128)
        xs[0][t] = bf2f(xl[(size_t)(TT - 1) * DD + dbase + t]);
    else
        xs[1][t - 128] = bf2f(xl[(size_t)(2 * TT - 1) * DD + dbase + (t - 128)]);
    __syncthreads();
    int v = blockIdx.x * 256 + t;
    float a0 = 0.f, a1 = 0.f;
    for (int i = 0; i < 128; ++i) {
        float wv = Wh[(size_t)(dbase + i) * VV + v];
        a0 += xs[0][i] * wv;
        a1 += xs[1][i] * wv;
    }
    atomicAdd(&out[v], a0);
    atomicAdd(&out[VV + v], a1);
}

// ---------------------------------------------------------------- launch
extern "C" void kernel_launch(void* const* d_in, const int* in_sizes, int n_in,
                              void* d_out, int out_size, void* d_ws, size_t ws_size,
                              hipStream_t stream) {
    const int*   idx  = (const int*)d_in[0];
    const float* tok  = (const float*)d_in[1];
    const float* pos  = (const float*)d_in[2];
    const float* ln1w = (const float*)d_in[3];
    const float* ln1b = (const float*)d_in[4];
    const float* qw   = (const float*)d_in[5];
    const float* qb   = (const float*)d_in[6];
    const float* kw   = (const float*)d_in[7];
    const float* kb   = (const float*)d_in[8];
    const float* vw   = (const float*)d_in[9];
    const float* vb   = (const float*)d_in[10];
    const float* ow   = (const float*)d_in[11];
    const float* ob   = (const float*)d_in[12];
    const float* ln2w = (const float*)d_in[13];
    const float* ln2b = (const float*)d_in[14];
    const float* f1w  = (const float*)d_in[15];
    const float* f1b  = (const float*)d_in[16];
    const float* f2w  = (const float*)d_in[17];
    const float* f2b  = (const float*)d_in[18];
    const float* lnfw = (const float*)d_in[19];
    const float* lnfb = (const float*)d_in[20];
    const float* hw   = (const float*)d_in[21];
    const float* hb   = (const float*)d_in[22];
    float* out = (float*)d_out;

    char* wsb = (char*)d_ws;
    float*          x  = (float*)wsb;                            // 8,388,608 B
    unsigned short* h  = (unsigned short*)(wsb + 8388608);       // 4,194,304 B
    unsigned short* qq = (unsigned short*)(wsb + 12582912);
    unsigned short* kk = (unsigned short*)(wsb + 16777216);
    unsigned short* vv = (unsigned short*)(wsb + 20971520);
    unsigned short* oo = (unsigned short*)(wsb + 25165824);
    unsigned short* ff = (unsigned short*)(wsb + 29360128);      // 16,777,216 B (ends 46,137,344)

    dim3 blk(256);
    k_embed<<<MM, blk, 0, stream>>>(idx, tok, pos, x);
    for (int l = 0; l < LL; ++l) {
        k_ln<<<MM, blk, 0, stream>>>(x, ln1w + l * DD, ln1b + l * DD, h);
        dim3 gqkv(DD / 128, MM / 128, 3);
        k_gemm_qkv<<<gqkv, blk, 0, stream>>>(
            h, qw + (size_t)l * DD * DD, kw + (size_t)l * DD * DD, vw + (size_t)l * DD * DD,
            qb + l * DD, kb + l * DD, vb + l * DD, qq, kk, vv, DD, DD);
        k_attn<<<BBATCH * HH * TT / 4, blk, 0, stream>>>(qq, kk, vv, oo);
        dim3 g1(DD / 128, MM / 128);
        k_gemm<2><<<g1, blk, 0, stream>>>(oo, ow + (size_t)l * DD * DD, ob + l * DD,
                                          nullptr, x, DD, DD);
        k_ln<<<MM, blk, 0, stream>>>(x, ln2w + l * DD, ln2b + l * DD, h);
        dim3 g2(FFD / 128, MM / 128);
        k_gemm<1><<<g2, blk, 0, stream>>>(h, f1w + (size_t)l * DD * FFD, f1b + l * FFD,
                                          ff, nullptr, DD, FFD);
        dim3 g3(DD / 128, MM / 128);
        k_gemm<2><<<g3, blk, 0, stream>>>(ff, f2w + (size_t)l * FFD * DD, f2b + l * DD,
                                          nullptr, x, FFD, DD);
    }
    k_ln<<<MM, blk, 0, stream>>>(x, lnfw, lnfb, h);
    k_head_init<<<VV / 256, blk, 0, stream>>>(hb, out);
    dim3 gh(VV / 256, 8);
    k_head<<<gh, blk, 0, stream>>>(h, hw, out);
}